// Round 9
// baseline (306.942 us; speedup 1.0000x reference)
//
#include <hip/hip_runtime.h>

#define LREL(x) ((x) > 0.0f ? (x) : 0.2f * (x))

// Zero cnt (2N ints) + bk[k] = sum_c b1cat[c]*W2[c,k] (layer-1 bias through layer-2 proj)
__global__ void k_prep(int* __restrict__ cnt, int n, const float* __restrict__ b1,
                       const float* __restrict__ W2, float* __restrict__ bk) {
    int i = blockIdx.x * blockDim.x + threadIdx.x;
    int st = gridDim.x * blockDim.x;
    for (; i < n; i += st) cnt[i] = 0;
    if (blockIdx.x == 0 && threadIdx.x < 2) {
        int k = threadIdx.x;
        float acc = 0.f;
#pragma unroll
        for (int c = 0; c < 256; ++c) acc = fmaf(b1[c & 127], W2[c * 2 + k], acc);
        bk[k] = acc;
    }
}

// Fused layer-1 projection: el1/er1 [N,2] and g [N][rel][h][k] (8 floats/node).
// h1 never touches memory. One block (128 thr = 2 waves) per node.
__global__ void k_gemm1g(const float* __restrict__ x, const float* __restrict__ W1,
                         const float* __restrict__ aL1, const float* __restrict__ aR1,
                         const float* __restrict__ W2,
                         float* __restrict__ el1, float* __restrict__ er1,
                         float* __restrict__ g, int N) {
    int n = blockIdx.x;
    int j = threadIdx.x;  // 0..127
    int h = j >> 6, lane = j & 63;
    __shared__ float xs[32];
    if (j < 32) xs[j] = x[(long)n * 32 + j];
    __syncthreads();
    float acc = 0.f;
#pragma unroll
    for (int k = 0; k < 32; ++k) acc = fmaf(xs[k], W1[k * 128 + j], acc);
    float vl = acc * aL1[j];
    float vr = acc * aR1[j];
    float2 w2r0 = *(const float2*)(W2 + 2 * j);
    float2 w2r1 = *(const float2*)(W2 + 2 * (128 + j));
    float g00 = acc * w2r0.x, g01 = acc * w2r0.y;
    float g10 = acc * w2r1.x, g11 = acc * w2r1.y;
#pragma unroll
    for (int off = 32; off; off >>= 1) {
        vl  += __shfl_down(vl, off);
        vr  += __shfl_down(vr, off);
        g00 += __shfl_down(g00, off);
        g01 += __shfl_down(g01, off);
        g10 += __shfl_down(g10, off);
        g11 += __shfl_down(g11, off);
    }
    if (lane == 0) {
        el1[n * 2 + h] = vl;
        er1[n * 2 + h] = vr;
        float* gp = g + (long)n * 8;  // [rel][h][k]
        gp[0 + h * 2 + 0] = g00;
        gp[0 + h * 2 + 1] = g01;
        gp[4 + h * 2 + 0] = g10;
        gp[4 + h * 2 + 1] = g11;
    }
}

// Degree histogram, fire-and-forget atomics. Bucket index b = 2*dst + rel.
__global__ void k_count(const int* __restrict__ dstF, const int* __restrict__ dstL,
                        int* __restrict__ cnt, int E) {
    int e = blockIdx.x * blockDim.x + threadIdx.x;
    if (e >= E) return;
    atomicAdd(&cnt[dstF[e] * 2 + 0], 1);
    atomicAdd(&cnt[dstL[e] * 2 + 1], 1);
}

// Hierarchical scan, stage 1: per-block (256) exclusive scan; block totals to bsum.
__global__ void k_scan1(const int* __restrict__ cnt, int* __restrict__ off,
                        int* __restrict__ bsum, int n) {
    __shared__ int ls[256];
    int i = blockIdx.x * 256 + threadIdx.x;
    int v = (i < n) ? cnt[i] : 0;
    ls[threadIdx.x] = v;
    __syncthreads();
    for (int o = 1; o < 256; o <<= 1) {
        int t = (threadIdx.x >= (unsigned)o) ? ls[threadIdx.x - o] : 0;
        __syncthreads();
        ls[threadIdx.x] += t;
        __syncthreads();
    }
    if (i < n) off[i] = ls[threadIdx.x] - v;  // block-local exclusive
    if (threadIdx.x == 255) bsum[blockIdx.x] = ls[255];
}

// Stage 2: single block, exclusive scan of nb (<512) block sums in place.
__global__ void k_scan2(int* __restrict__ bsum, int nb) {
    __shared__ int ls[512];
    int tid = threadIdx.x;
    int v = (tid < nb) ? bsum[tid] : 0;
    ls[tid] = v;
    __syncthreads();
    for (int o = 1; o < 512; o <<= 1) {
        int t = (tid >= o) ? ls[tid - o] : 0;
        __syncthreads();
        ls[tid] += t;
        __syncthreads();
    }
    if (tid < nb) bsum[tid] = ls[tid] - v;  // exclusive
}

// Stage 3: add block base; copy to place-cursors; write off[n] = 2E.
__global__ void k_scan3(int* __restrict__ off, const int* __restrict__ bsum,
                        int* __restrict__ cur, int n, int total) {
    int i = blockIdx.x * 256 + threadIdx.x;
    if (i < n) {
        int o = off[i] + bsum[blockIdx.x];
        off[i] = o;
        cur[i] = o;
    }
    if (i == 0) off[n] = total;
}

// Place SRC NODE IDS into compact CSR buckets. Slot order is replay-varying;
// each bucket's set is exact (capacity == degree). Plain 4B store (R8 proved
// cross-kernel visibility of plain stores).
__global__ void k_place(const int* __restrict__ srcF, const int* __restrict__ dstF,
                        const int* __restrict__ srcL, const int* __restrict__ dstL,
                        int* __restrict__ cur, int* __restrict__ bkt, int E) {
    int e = blockIdx.x * blockDim.x + threadIdx.x;
    if (e >= E) return;
    {
        int s = srcF[e];
        int p = atomicAdd(&cur[dstF[e] * 2 + 0], 1);
        bkt[p] = s;
    }
    {
        int s = srcL[e];
        int p = atomicAdd(&cur[dstL[e] * 2 + 1], 1);
        bkt[p] = s;
    }
}

// Layer-1 softmax-aggregation in g-space + cross-(rel,h) combine into h2.
// Thread t = 2d+rel (= bucket id). Pair (2d,2d+1) exchanges via LDS.
// Grid is XCD-swizzled: each XCD reads a contiguous bkt slice.
__global__ void k_agg1(const int* __restrict__ off, const int* __restrict__ bkt,
                       const float* __restrict__ el1, const float* __restrict__ er1,
                       const float* __restrict__ g, const float* __restrict__ bk,
                       float* __restrict__ h2, int N) {
    __shared__ float4 sh[256];
    int chunk = gridDim.x >> 3;  // gridDim.x % 8 == 0
    int sb = ((blockIdx.x & 7) * chunk) + (blockIdx.x >> 3);
    int t = sb * 256 + threadIdx.x;
    int d = t >> 1, rel = t & 1;
    float4 r = make_float4(0.f, 0.f, 0.f, 0.f);
    if (d < N) {
        int j0 = off[t], j1 = off[t + 1];
        float2 erd = *(const float2*)(er1 + 2 * d);
        float n00 = 0.f, n01 = 0.f, n10 = 0.f, n11 = 0.f, ws0 = 0.f, ws1 = 0.f;
        for (int j = j0; j < j1; ++j) {
            int s = bkt[j];
            float2 els = *(const float2*)(el1 + 2 * s);
            float4 gv = *(const float4*)(g + (long)s * 8 + rel * 4);
            float w0 = __expf(LREL(els.x + erd.x));
            float w1 = __expf(LREL(els.y + erd.y));
            n00 = fmaf(w0, gv.x, n00);
            n01 = fmaf(w0, gv.y, n01);
            n10 = fmaf(w1, gv.z, n10);
            n11 = fmaf(w1, gv.w, n11);
            ws0 += w0;
            ws1 += w1;
        }
        if (j1 > j0) {
            r.x = n00 / ws0; r.y = n01 / ws0;
            r.z = n10 / ws1; r.w = n11 / ws1;
        }
    }
    sh[threadIdx.x] = r;
    __syncthreads();
    if (d < N && rel == 0) {
        float4 q = sh[threadIdx.x + 1];  // partner: same d, rel=1
        float2 o;
        o.x = bk[0] + r.x + r.z + q.x + q.z;
        o.y = bk[1] + r.y + r.w + q.y + q.w;
        *(float2*)(h2 + 2 * d) = o;
    }
}

// Layer-2 softmax-aggregation + output. Thread t = 2d+rel; float2 store. O=1.
__global__ void k_agg2(const int* __restrict__ off, const int* __restrict__ bkt,
                       const float* __restrict__ h2, const float* __restrict__ aL2,
                       const float* __restrict__ aR2, const float* __restrict__ b2,
                       float* __restrict__ out, int N) {
    int chunk = gridDim.x >> 3;
    int sb = ((blockIdx.x & 7) * chunk) + (blockIdx.x >> 3);
    int t = sb * 256 + threadIdx.x;
    int d = t >> 1, rel = t & 1;
    if (d >= N) return;
    int j0 = off[t], j1 = off[t + 1];
    float aL0 = aL2[0], aL1_ = aL2[1];
    float2 hd = *(const float2*)(h2 + 2 * d);
    float er0 = hd.x * aR2[0], er1_ = hd.y * aR2[1];
    float n0 = 0.f, n1 = 0.f, s0 = 0.f, s1 = 0.f;
    for (int j = j0; j < j1; ++j) {
        int s = bkt[j];
        float2 hs = *(const float2*)(h2 + 2 * s);
        float w0 = __expf(LREL(hs.x * aL0 + er0));
        float w1 = __expf(LREL(hs.y * aL1_ + er1_));
        n0 = fmaf(w0, hs.x, n0);
        n1 = fmaf(w1, hs.y, n1);
        s0 += w0;
        s1 += w1;
    }
    int deg = j1 - j0;
    float2 o;
    o.x = (deg ? n0 / s0 : 0.f) + b2[0];
    o.y = (deg ? n1 / s1 : 0.f) + b2[1];
    *(float2*)(out + (long)d * 4 + rel * 2) = o;
}

extern "C" void kernel_launch(void* const* d_in, const int* in_sizes, int n_in,
                              void* d_out, int out_size, void* d_ws, size_t ws_size,
                              hipStream_t stream) {
    const float* x   = (const float*)d_in[0];
    const float* W1  = (const float*)d_in[1];
    const float* aL1 = (const float*)d_in[2];
    const float* aR1 = (const float*)d_in[3];
    const float* b1  = (const float*)d_in[4];
    const float* W2  = (const float*)d_in[5];
    const float* aL2 = (const float*)d_in[6];
    const float* aR2 = (const float*)d_in[7];
    const float* b2  = (const float*)d_in[8];
    const int* srcF  = (const int*)d_in[9];
    const int* dstF  = (const int*)d_in[10];
    const int* srcL  = (const int*)d_in[11];
    const int* dstL  = (const int*)d_in[12];
    float* out = (float*)d_out;

    const int N = in_sizes[0] / 32;
    const int E = in_sizes[9];
    const int n = 2 * N;  // number of (dst, rel) buckets

    // Workspace: el1 2N | er1 2N | g 8N | h2 2N | bk 16 || cnt 2N | off 2N+1 | cur 2N | bsum 512 | bkt 2E
    float* ws  = (float*)d_ws;
    float* el1 = ws;                       // 2N
    float* er1 = el1 + (long)2 * N;        // 2N
    float* g   = er1 + (long)2 * N;        // 8N (byte offset 16N — 16B-aligned)
    float* h2  = g + (long)8 * N;          // 2N
    float* bk  = h2 + (long)2 * N;         // 16
    int* cnt   = (int*)(bk + 16);          // 2N
    int* off   = cnt + (long)n;            // 2N+1
    int* cur   = off + (long)n + 1;        // 2N
    int* bsum  = cur + (long)n;            // 512
    int* bkt   = bsum + 512;               // 2E (compact; holds SRC ids)
    // total ~= 11 MB

    k_prep<<<128, 256, 0, stream>>>(cnt, n, b1, W2, bk);
    k_gemm1g<<<N, 128, 0, stream>>>(x, W1, aL1, aR1, W2, el1, er1, g, N);

    int eb = (E + 255) / 256;
    k_count<<<eb, 256, 0, stream>>>(dstF, dstL, cnt, E);

    int nb = (n + 255) / 256;  // 391 scan blocks (<= 512)
    k_scan1<<<nb, 256, 0, stream>>>(cnt, off, bsum, n);
    k_scan2<<<1, 512, 0, stream>>>(bsum, nb);
    k_scan3<<<nb, 256, 0, stream>>>(off, bsum, cur, n, 2 * E);

    k_place<<<eb, 256, 0, stream>>>(srcF, dstF, srcL, dstL, cur, bkt, E);

    int ab = ((nb + 7) / 8) * 8;  // agg grid, multiple of 8 for XCD swizzle
    k_agg1<<<ab, 256, 0, stream>>>(off, bkt, el1, er1, g, bk, h2, N);
    k_agg2<<<ab, 256, 0, stream>>>(off, bkt, h2, aL2, aR2, b2, out, N);
}

// Round 10
// 169.824 us; speedup vs baseline: 1.8074x; 1.8074x over previous
//
#include <hip/hip_runtime.h>

#define LREL(x) ((x) > 0.0f ? (x) : 0.2f * (x))
#define TILE1 6250   // dsts per tile; 8 tiles cover N=50000
#define SLICES 16

// bk[k] = sum_c b1cat[c]*W2[c,k] (layer-1 bias pushed through the linear layer-2 proj)
__global__ void k_prep(const float* __restrict__ b1, const float* __restrict__ W2,
                       float* __restrict__ bk) {
    int k = threadIdx.x;
    if (k >= 2) return;
    float acc = 0.f;
#pragma unroll
    for (int c = 0; c < 256; ++c) acc = fmaf(b1[c & 127], W2[c * 2 + k], acc);
    bk[k] = acc;
}

// Fused layer-1 projection: el1/er1 [N,2] and g [N][rel][h][k] (8 floats/node).
// h1 never touches memory. One block (128 thr = 2 waves) per node.
__global__ void k_gemm1g(const float* __restrict__ x, const float* __restrict__ W1,
                         const float* __restrict__ aL1, const float* __restrict__ aR1,
                         const float* __restrict__ W2,
                         float* __restrict__ el1, float* __restrict__ er1,
                         float* __restrict__ g, int N) {
    int n = blockIdx.x;
    int j = threadIdx.x;  // 0..127
    int h = j >> 6, lane = j & 63;
    __shared__ float xs[32];
    if (j < 32) xs[j] = x[(long)n * 32 + j];
    __syncthreads();
    float acc = 0.f;
#pragma unroll
    for (int k = 0; k < 32; ++k) acc = fmaf(xs[k], W1[k * 128 + j], acc);
    float vl = acc * aL1[j];
    float vr = acc * aR1[j];
    float2 w2r0 = *(const float2*)(W2 + 2 * j);
    float2 w2r1 = *(const float2*)(W2 + 2 * (128 + j));
    float g00 = acc * w2r0.x, g01 = acc * w2r0.y;
    float g10 = acc * w2r1.x, g11 = acc * w2r1.y;
#pragma unroll
    for (int off = 32; off; off >>= 1) {
        vl  += __shfl_down(vl, off);
        vr  += __shfl_down(vr, off);
        g00 += __shfl_down(g00, off);
        g01 += __shfl_down(g01, off);
        g10 += __shfl_down(g10, off);
        g11 += __shfl_down(g11, off);
    }
    if (lane == 0) {
        el1[n * 2 + h] = vl;
        er1[n * 2 + h] = vr;
        float* gp = g + (long)n * 8;  // [rel][h][k]
        gp[0 + h * 2 + 0] = g00;
        gp[0 + h * 2 + 1] = g01;
        gp[4 + h * 2 + 0] = g10;
        gp[4 + h * 2 + 1] = g11;
    }
}

// Layer-1 tiled segment-reduction. Block (slice s, tile t, rel): stream edge slice
// linearly, filter dst to tile, LDS-atomic into bins[dl][6]={n00,n01,n10,n11,w0,w1},
// dump contiguously to partial1[rel][t][s]. Zero scattered global writes.
__global__ void k_agg1t(const int* __restrict__ srcF, const int* __restrict__ dstF,
                        const int* __restrict__ srcL, const int* __restrict__ dstL,
                        const float* __restrict__ el1, const float* __restrict__ er1,
                        const float* __restrict__ g, float* __restrict__ partial1,
                        int E, int tiles) {
    __shared__ float bins[TILE1 * 6];  // 150,000 B
    int s = blockIdx.x, t = blockIdx.y, rel = blockIdx.z;
    const int* src = rel ? srcL : srcF;
    const int* dst = rel ? dstL : dstF;
    int base = t * TILE1;

    for (int i = threadIdx.x; i < TILE1 * 6 / 4; i += blockDim.x)
        ((float4*)bins)[i] = make_float4(0.f, 0.f, 0.f, 0.f);
    __syncthreads();

    int chunk = (((E + SLICES - 1) / SLICES) + 3) & ~3;
    int e0 = s * chunk;
    int e1 = e0 + chunk; if (e1 > E) e1 = E; if (e0 > E) e0 = E;
    int n4 = (e1 - e0) / 4;
    const int4* dp = (const int4*)(dst + e0);
    const int4* sp = (const int4*)(src + e0);
    for (int i = threadIdx.x; i < n4; i += blockDim.x) {
        int4 dv = dp[i];
        int4 sv = sp[i];
#pragma unroll
        for (int u = 0; u < 4; ++u) {
            int d = (&dv.x)[u];
            unsigned dl = (unsigned)(d - base);
            if (dl < TILE1) {
                int sn = (&sv.x)[u];
                float2 els = *(const float2*)(el1 + 2 * sn);
                float2 erd = *(const float2*)(er1 + 2 * d);
                float4 gv = *(const float4*)(g + (long)sn * 8 + rel * 4);
                float w0 = __expf(LREL(els.x + erd.x));
                float w1 = __expf(LREL(els.y + erd.y));
                float* b = bins + dl * 6;
                atomicAdd(b + 0, w0 * gv.x);
                atomicAdd(b + 1, w0 * gv.y);
                atomicAdd(b + 2, w1 * gv.z);
                atomicAdd(b + 3, w1 * gv.w);
                atomicAdd(b + 4, w0);
                atomicAdd(b + 5, w1);
            }
        }
    }
    for (int e = e0 + n4 * 4 + threadIdx.x; e < e1; e += blockDim.x) {  // tail
        int d = dst[e];
        unsigned dl = (unsigned)(d - base);
        if (dl < TILE1) {
            int sn = src[e];
            float2 els = *(const float2*)(el1 + 2 * sn);
            float2 erd = *(const float2*)(er1 + 2 * d);
            float4 gv = *(const float4*)(g + (long)sn * 8 + rel * 4);
            float w0 = __expf(LREL(els.x + erd.x));
            float w1 = __expf(LREL(els.y + erd.y));
            float* b = bins + dl * 6;
            atomicAdd(b + 0, w0 * gv.x);
            atomicAdd(b + 1, w0 * gv.y);
            atomicAdd(b + 2, w1 * gv.z);
            atomicAdd(b + 3, w1 * gv.w);
            atomicAdd(b + 4, w0);
            atomicAdd(b + 5, w1);
        }
    }
    __syncthreads();
    float* dstp = partial1 + (((long)rel * tiles + t) * SLICES + s) * (TILE1 * 6);
    for (int i = threadIdx.x; i < TILE1 * 6 / 4; i += blockDim.x)
        ((float4*)dstp)[i] = ((const float4*)bins)[i];
}

// Merge layer-1 partials over slices; combine (rel,h) into h2[d,0:2].
__global__ void k_merge1(const float* __restrict__ partial1, const float* __restrict__ bk,
                         float* __restrict__ h2, int N, int tiles) {
    int d = blockIdx.x * blockDim.x + threadIdx.x;
    if (d >= N) return;
    int t = d / TILE1, dl = d % TILE1;
    float r0 = bk[0], r1 = bk[1];
#pragma unroll
    for (int rel = 0; rel < 2; ++rel) {
        const float* p = partial1 + (((long)rel * tiles + t) * SLICES) * (TILE1 * 6) + (long)dl * 6;
        float n00 = 0.f, n01 = 0.f, n10 = 0.f, n11 = 0.f, w0 = 0.f, w1 = 0.f;
        for (int s = 0; s < SLICES; ++s) {
            const float* q = p + (long)s * (TILE1 * 6);
            float2 a = *(const float2*)(q + 0);
            float2 b = *(const float2*)(q + 2);
            float2 c = *(const float2*)(q + 4);
            n00 += a.x; n01 += a.y;
            n10 += b.x; n11 += b.y;
            w0  += c.x; w1  += c.y;
        }
        if (w0 > 0.f) { r0 += n00 / w0; r1 += n01 / w0; }
        if (w1 > 0.f) { r0 += n10 / w1; r1 += n11 / w1; }
    }
    *(float2*)(h2 + 2 * d) = make_float2(r0, r1);
}

// Layer-2 tiled segment-reduction: bins[dl][4] = {n0, n1, w0sum, w1sum}.
__global__ void k_agg2t(const int* __restrict__ srcF, const int* __restrict__ dstF,
                        const int* __restrict__ srcL, const int* __restrict__ dstL,
                        const float* __restrict__ h2, const float* __restrict__ aL2,
                        const float* __restrict__ aR2, float* __restrict__ partial2,
                        int E, int tiles) {
    __shared__ float bins[TILE1 * 4];  // 100,000 B
    int s = blockIdx.x, t = blockIdx.y, rel = blockIdx.z;
    const int* src = rel ? srcL : srcF;
    const int* dst = rel ? dstL : dstF;
    int base = t * TILE1;
    float aL0 = aL2[0], aL1_ = aL2[1], aR0 = aR2[0], aR1_ = aR2[1];

    for (int i = threadIdx.x; i < TILE1; i += blockDim.x)
        ((float4*)bins)[i] = make_float4(0.f, 0.f, 0.f, 0.f);
    __syncthreads();

    int chunk = (((E + SLICES - 1) / SLICES) + 3) & ~3;
    int e0 = s * chunk;
    int e1 = e0 + chunk; if (e1 > E) e1 = E; if (e0 > E) e0 = E;
    int n4 = (e1 - e0) / 4;
    const int4* dp = (const int4*)(dst + e0);
    const int4* sp = (const int4*)(src + e0);
    for (int i = threadIdx.x; i < n4; i += blockDim.x) {
        int4 dv = dp[i];
        int4 sv = sp[i];
#pragma unroll
        for (int u = 0; u < 4; ++u) {
            int d = (&dv.x)[u];
            unsigned dl = (unsigned)(d - base);
            if (dl < TILE1) {
                int sn = (&sv.x)[u];
                float2 hs = *(const float2*)(h2 + 2 * sn);
                float2 hd = *(const float2*)(h2 + 2 * d);
                float w0 = __expf(LREL(hs.x * aL0 + hd.x * aR0));
                float w1 = __expf(LREL(hs.y * aL1_ + hd.y * aR1_));
                float* b = bins + dl * 4;
                atomicAdd(b + 0, w0 * hs.x);
                atomicAdd(b + 1, w1 * hs.y);
                atomicAdd(b + 2, w0);
                atomicAdd(b + 3, w1);
            }
        }
    }
    for (int e = e0 + n4 * 4 + threadIdx.x; e < e1; e += blockDim.x) {  // tail
        int d = dst[e];
        unsigned dl = (unsigned)(d - base);
        if (dl < TILE1) {
            int sn = src[e];
            float2 hs = *(const float2*)(h2 + 2 * sn);
            float2 hd = *(const float2*)(h2 + 2 * d);
            float w0 = __expf(LREL(hs.x * aL0 + hd.x * aR0));
            float w1 = __expf(LREL(hs.y * aL1_ + hd.y * aR1_));
            float* b = bins + dl * 4;
            atomicAdd(b + 0, w0 * hs.x);
            atomicAdd(b + 1, w1 * hs.y);
            atomicAdd(b + 2, w0);
            atomicAdd(b + 3, w1);
        }
    }
    __syncthreads();
    float* dstp = partial2 + (((long)rel * tiles + t) * SLICES + s) * (TILE1 * 4);
    for (int i = threadIdx.x; i < TILE1; i += blockDim.x)
        ((float4*)dstp)[i] = ((const float4*)bins)[i];
}

// Merge layer-2 partials; final out[d, rel*2+h] = n_h/w_h + b2[h].
__global__ void k_merge2(const float* __restrict__ partial2, const float* __restrict__ b2,
                         float* __restrict__ out, int N, int tiles) {
    int d = blockIdx.x * blockDim.x + threadIdx.x;
    if (d >= N) return;
    int t = d / TILE1, dl = d % TILE1;
    float b20 = b2[0], b21 = b2[1];
    float4 o;
#pragma unroll
    for (int rel = 0; rel < 2; ++rel) {
        const float* p = partial2 + (((long)rel * tiles + t) * SLICES) * (TILE1 * 4) + (long)dl * 4;
        float n0 = 0.f, n1 = 0.f, w0 = 0.f, w1 = 0.f;
        for (int s = 0; s < SLICES; ++s) {
            float4 q = *(const float4*)(p + (long)s * (TILE1 * 4));
            n0 += q.x; n1 += q.y; w0 += q.z; w1 += q.w;
        }
        float o0 = (w0 > 0.f ? n0 / w0 : 0.f) + b20;
        float o1 = (w1 > 0.f ? n1 / w1 : 0.f) + b21;
        if (rel == 0) { o.x = o0; o.y = o1; } else { o.z = o0; o.w = o1; }
    }
    *(float4*)(out + (long)d * 4) = o;
}

extern "C" void kernel_launch(void* const* d_in, const int* in_sizes, int n_in,
                              void* d_out, int out_size, void* d_ws, size_t ws_size,
                              hipStream_t stream) {
    const float* x   = (const float*)d_in[0];
    const float* W1  = (const float*)d_in[1];
    const float* aL1 = (const float*)d_in[2];
    const float* aR1 = (const float*)d_in[3];
    const float* b1  = (const float*)d_in[4];
    const float* W2  = (const float*)d_in[5];
    const float* aL2 = (const float*)d_in[6];
    const float* aR2 = (const float*)d_in[7];
    const float* b2  = (const float*)d_in[8];
    const int* srcF  = (const int*)d_in[9];
    const int* dstF  = (const int*)d_in[10];
    const int* srcL  = (const int*)d_in[11];
    const int* dstL  = (const int*)d_in[12];
    float* out = (float*)d_out;

    const int N = in_sizes[0] / 32;
    const int E = in_sizes[9];
    const int tiles = (N + TILE1 - 1) / TILE1;  // 8 for N=50000

    // Workspace: el1 2N | er1 2N | g 8N | h2 2N | bk 16 | partial1 2*tiles*16*TILE1*6 | partial2 2*tiles*16*TILE1*4
    float* ws   = (float*)d_ws;
    float* el1  = ws;                             // 2N
    float* er1  = el1 + (long)2 * N;              // 2N
    float* g    = er1 + (long)2 * N;              // 8N (byte off 16N — 16B-aligned)
    float* h2   = g + (long)8 * N;                // 2N
    float* bk   = h2 + (long)2 * N;               // 16
    float* partial1 = bk + 16;                    // 2*tiles*SLICES*TILE1*6 (= 38.4 MB)
    float* partial2 = partial1 + (long)2 * tiles * SLICES * TILE1 * 6;  // (= 25.6 MB)
    // total ~= 64 MB + 5.6 MB tables (ws proven >= 81 MB in round 2)

    k_prep<<<1, 64, 0, stream>>>(b1, W2, bk);
    k_gemm1g<<<N, 128, 0, stream>>>(x, W1, aL1, aR1, W2, el1, er1, g, N);

    dim3 agrid(SLICES, tiles, 2);
    k_agg1t<<<agrid, 512, 0, stream>>>(srcF, dstF, srcL, dstL, el1, er1, g, partial1, E, tiles);
    k_merge1<<<(N + 255) / 256, 256, 0, stream>>>(partial1, bk, h2, N, tiles);
    k_agg2t<<<agrid, 512, 0, stream>>>(srcF, dstF, srcL, dstL, h2, aL2, aR2, partial2, E, tiles);
    k_merge2<<<(N + 255) / 256, 256, 0, stream>>>(partial2, b2, out, N, tiles);
}

// Round 11
// 136.748 us; speedup vs baseline: 2.2446x; 1.2419x over previous
//
#include <hip/hip_runtime.h>

#define LREL(x) ((x) > 0.0f ? (x) : 0.2f * (x))
#define TILE1 6250   // dsts per tile; 8 tiles cover N=50000
#define SLICES 16

// Precompute reduced projection weights pw[32][12] and bias-through term bk[2].
// pw[k][q]: q=0,1 -> el head q; q=2,3 -> er head q-2;
//           q=4..11 -> g with (q-4) = rel*4 + h*2 + kk:
//           sum_{o<64} W1[k][h*64+o] * W2[(rel*128+h*64+o)*2+kk]
__global__ void k_precomp(const float* __restrict__ W1, const float* __restrict__ aL1,
                          const float* __restrict__ aR1, const float* __restrict__ W2,
                          const float* __restrict__ b1, float* __restrict__ pw,
                          float* __restrict__ bk) {
    int tid = threadIdx.x;
    if (tid < 384) {
        int k = tid / 12, q = tid % 12;
        float acc = 0.f;
        if (q < 2) {
            int h = q;
#pragma unroll
            for (int o = 0; o < 64; ++o) acc = fmaf(W1[k * 128 + h * 64 + o], aL1[h * 64 + o], acc);
        } else if (q < 4) {
            int h = q - 2;
#pragma unroll
            for (int o = 0; o < 64; ++o) acc = fmaf(W1[k * 128 + h * 64 + o], aR1[h * 64 + o], acc);
        } else {
            int r = q - 4;
            int rel = r >> 2, h = (r >> 1) & 1, kk = r & 1;
#pragma unroll
            for (int o = 0; o < 64; ++o)
                acc = fmaf(W1[k * 128 + h * 64 + o], W2[(rel * 128 + h * 64 + o) * 2 + kk], acc);
        }
        pw[k * 12 + q] = acc;
    } else if (tid < 386) {
        int k = tid - 384;
        float acc = 0.f;
#pragma unroll
        for (int c = 0; c < 256; ++c) acc = fmaf(b1[c & 127], W2[c * 2 + k], acc);
        bk[k] = acc;
    }
}

// Collapsed layer-1 projection: [N,32] x [32,12] -> el1 [N,2], er1 [N,2], g [N,8].
// One thread per node; no shuffles, no h1, weights broadcast from LDS.
__global__ void k_proj(const float* __restrict__ x, const float* __restrict__ pw,
                       float* __restrict__ el1, float* __restrict__ er1,
                       float* __restrict__ g, int N) {
    __shared__ float ps[384];
    for (int i = threadIdx.x; i < 384; i += 256) ps[i] = pw[i];
    __syncthreads();
    int n = blockIdx.x * 256 + threadIdx.x;
    if (n >= N) return;
    float xr[32];
#pragma unroll
    for (int u = 0; u < 8; ++u) {
        float4 v = *(const float4*)(x + (long)n * 32 + u * 4);
        xr[u * 4 + 0] = v.x; xr[u * 4 + 1] = v.y;
        xr[u * 4 + 2] = v.z; xr[u * 4 + 3] = v.w;
    }
    float o[12];
#pragma unroll
    for (int q = 0; q < 12; ++q) o[q] = 0.f;
#pragma unroll
    for (int k = 0; k < 32; ++k) {
        float xv = xr[k];
#pragma unroll
        for (int q = 0; q < 12; ++q) o[q] = fmaf(xv, ps[k * 12 + q], o[q]);
    }
    *(float2*)(el1 + 2 * n) = make_float2(o[0], o[1]);
    *(float2*)(er1 + 2 * n) = make_float2(o[2], o[3]);
    *(float4*)(g + (long)n * 8)     = make_float4(o[4], o[5], o[6], o[7]);
    *(float4*)(g + (long)n * 8 + 4) = make_float4(o[8], o[9], o[10], o[11]);
}

// Layer-1 tiled segment-reduction. Block (slice s, tile t, rel): stream edge slice
// linearly, filter dst to tile, LDS-atomic into bins[dl][6]={n00,n01,n10,n11,w0,w1},
// dump contiguously to partial1[rel][t][s]. Zero scattered global writes.
// 1024 threads: 16 waves/CU (LDS caps at 1 block/CU).
__global__ void k_agg1t(const int* __restrict__ srcF, const int* __restrict__ dstF,
                        const int* __restrict__ srcL, const int* __restrict__ dstL,
                        const float* __restrict__ el1, const float* __restrict__ er1,
                        const float* __restrict__ g, float* __restrict__ partial1,
                        int E, int tiles) {
    __shared__ float bins[TILE1 * 6];  // 150,000 B
    int s = blockIdx.x, t = blockIdx.y, rel = blockIdx.z;
    const int* src = rel ? srcL : srcF;
    const int* dst = rel ? dstL : dstF;
    int base = t * TILE1;

    for (int i = threadIdx.x; i < TILE1 * 6 / 4; i += blockDim.x)
        ((float4*)bins)[i] = make_float4(0.f, 0.f, 0.f, 0.f);
    __syncthreads();

    int chunk = (((E + SLICES - 1) / SLICES) + 3) & ~3;
    int e0 = s * chunk;
    int e1 = e0 + chunk; if (e1 > E) e1 = E; if (e0 > E) e0 = E;
    int n4 = (e1 - e0) / 4;
    const int4* dp = (const int4*)(dst + e0);
    const int4* sp = (const int4*)(src + e0);
    for (int i = threadIdx.x; i < n4; i += blockDim.x) {
        int4 dv = dp[i];
        int4 sv = sp[i];
#pragma unroll
        for (int u = 0; u < 4; ++u) {
            int d = (&dv.x)[u];
            unsigned dl = (unsigned)(d - base);
            if (dl < TILE1) {
                int sn = (&sv.x)[u];
                float2 els = *(const float2*)(el1 + 2 * sn);
                float2 erd = *(const float2*)(er1 + 2 * d);
                float4 gv = *(const float4*)(g + (long)sn * 8 + rel * 4);
                float w0 = __expf(LREL(els.x + erd.x));
                float w1 = __expf(LREL(els.y + erd.y));
                float* b = bins + dl * 6;
                atomicAdd(b + 0, w0 * gv.x);
                atomicAdd(b + 1, w0 * gv.y);
                atomicAdd(b + 2, w1 * gv.z);
                atomicAdd(b + 3, w1 * gv.w);
                atomicAdd(b + 4, w0);
                atomicAdd(b + 5, w1);
            }
        }
    }
    for (int e = e0 + n4 * 4 + threadIdx.x; e < e1; e += blockDim.x) {  // tail
        int d = dst[e];
        unsigned dl = (unsigned)(d - base);
        if (dl < TILE1) {
            int sn = src[e];
            float2 els = *(const float2*)(el1 + 2 * sn);
            float2 erd = *(const float2*)(er1 + 2 * d);
            float4 gv = *(const float4*)(g + (long)sn * 8 + rel * 4);
            float w0 = __expf(LREL(els.x + erd.x));
            float w1 = __expf(LREL(els.y + erd.y));
            float* b = bins + dl * 6;
            atomicAdd(b + 0, w0 * gv.x);
            atomicAdd(b + 1, w0 * gv.y);
            atomicAdd(b + 2, w1 * gv.z);
            atomicAdd(b + 3, w1 * gv.w);
            atomicAdd(b + 4, w0);
            atomicAdd(b + 5, w1);
        }
    }
    __syncthreads();
    float* dstp = partial1 + (((long)rel * tiles + t) * SLICES + s) * (TILE1 * 6);
    for (int i = threadIdx.x; i < TILE1 * 6 / 4; i += blockDim.x)
        ((float4*)dstp)[i] = ((const float4*)bins)[i];
}

// Merge layer-1 partials over slices; combine (rel,h) into h2[d,0:2].
__global__ void k_merge1(const float* __restrict__ partial1, const float* __restrict__ bk,
                         float* __restrict__ h2, int N, int tiles) {
    int d = blockIdx.x * blockDim.x + threadIdx.x;
    if (d >= N) return;
    int t = d / TILE1, dl = d % TILE1;
    float r0 = bk[0], r1 = bk[1];
#pragma unroll
    for (int rel = 0; rel < 2; ++rel) {
        const float* p = partial1 + (((long)rel * tiles + t) * SLICES) * (TILE1 * 6) + (long)dl * 6;
        float n00 = 0.f, n01 = 0.f, n10 = 0.f, n11 = 0.f, w0 = 0.f, w1 = 0.f;
        for (int s = 0; s < SLICES; ++s) {
            const float* q = p + (long)s * (TILE1 * 6);
            float2 a = *(const float2*)(q + 0);
            float2 b = *(const float2*)(q + 2);
            float2 c = *(const float2*)(q + 4);
            n00 += a.x; n01 += a.y;
            n10 += b.x; n11 += b.y;
            w0  += c.x; w1  += c.y;
        }
        if (w0 > 0.f) { r0 += n00 / w0; r1 += n01 / w0; }
        if (w1 > 0.f) { r0 += n10 / w1; r1 += n11 / w1; }
    }
    *(float2*)(h2 + 2 * d) = make_float2(r0, r1);
}

// Layer-2 tiled segment-reduction: bins[dl][4] = {n0, n1, w0sum, w1sum}. 1024 threads.
__global__ void k_agg2t(const int* __restrict__ srcF, const int* __restrict__ dstF,
                        const int* __restrict__ srcL, const int* __restrict__ dstL,
                        const float* __restrict__ h2, const float* __restrict__ aL2,
                        const float* __restrict__ aR2, float* __restrict__ partial2,
                        int E, int tiles) {
    __shared__ float bins[TILE1 * 4];  // 100,000 B
    int s = blockIdx.x, t = blockIdx.y, rel = blockIdx.z;
    const int* src = rel ? srcL : srcF;
    const int* dst = rel ? dstL : dstF;
    int base = t * TILE1;
    float aL0 = aL2[0], aL1_ = aL2[1], aR0 = aR2[0], aR1_ = aR2[1];

    for (int i = threadIdx.x; i < TILE1; i += blockDim.x)
        ((float4*)bins)[i] = make_float4(0.f, 0.f, 0.f, 0.f);
    __syncthreads();

    int chunk = (((E + SLICES - 1) / SLICES) + 3) & ~3;
    int e0 = s * chunk;
    int e1 = e0 + chunk; if (e1 > E) e1 = E; if (e0 > E) e0 = E;
    int n4 = (e1 - e0) / 4;
    const int4* dp = (const int4*)(dst + e0);
    const int4* sp = (const int4*)(src + e0);
    for (int i = threadIdx.x; i < n4; i += blockDim.x) {
        int4 dv = dp[i];
        int4 sv = sp[i];
#pragma unroll
        for (int u = 0; u < 4; ++u) {
            int d = (&dv.x)[u];
            unsigned dl = (unsigned)(d - base);
            if (dl < TILE1) {
                int sn = (&sv.x)[u];
                float2 hs = *(const float2*)(h2 + 2 * sn);
                float2 hd = *(const float2*)(h2 + 2 * d);
                float w0 = __expf(LREL(hs.x * aL0 + hd.x * aR0));
                float w1 = __expf(LREL(hs.y * aL1_ + hd.y * aR1_));
                float* b = bins + dl * 4;
                atomicAdd(b + 0, w0 * hs.x);
                atomicAdd(b + 1, w1 * hs.y);
                atomicAdd(b + 2, w0);
                atomicAdd(b + 3, w1);
            }
        }
    }
    for (int e = e0 + n4 * 4 + threadIdx.x; e < e1; e += blockDim.x) {  // tail
        int d = dst[e];
        unsigned dl = (unsigned)(d - base);
        if (dl < TILE1) {
            int sn = src[e];
            float2 hs = *(const float2*)(h2 + 2 * sn);
            float2 hd = *(const float2*)(h2 + 2 * d);
            float w0 = __expf(LREL(hs.x * aL0 + hd.x * aR0));
            float w1 = __expf(LREL(hs.y * aL1_ + hd.y * aR1_));
            float* b = bins + dl * 4;
            atomicAdd(b + 0, w0 * hs.x);
            atomicAdd(b + 1, w1 * hs.y);
            atomicAdd(b + 2, w0);
            atomicAdd(b + 3, w1);
        }
    }
    __syncthreads();
    float* dstp = partial2 + (((long)rel * tiles + t) * SLICES + s) * (TILE1 * 4);
    for (int i = threadIdx.x; i < TILE1; i += blockDim.x)
        ((float4*)dstp)[i] = ((const float4*)bins)[i];
}

// Merge layer-2 partials; final out[d, rel*2+h] = n_h/w_h + b2[h].
__global__ void k_merge2(const float* __restrict__ partial2, const float* __restrict__ b2,
                         float* __restrict__ out, int N, int tiles) {
    int d = blockIdx.x * blockDim.x + threadIdx.x;
    if (d >= N) return;
    int t = d / TILE1, dl = d % TILE1;
    float b20 = b2[0], b21 = b2[1];
    float4 o;
#pragma unroll
    for (int rel = 0; rel < 2; ++rel) {
        const float* p = partial2 + (((long)rel * tiles + t) * SLICES) * (TILE1 * 4) + (long)dl * 4;
        float n0 = 0.f, n1 = 0.f, w0 = 0.f, w1 = 0.f;
        for (int s = 0; s < SLICES; ++s) {
            float4 q = *(const float4*)(p + (long)s * (TILE1 * 4));
            n0 += q.x; n1 += q.y; w0 += q.z; w1 += q.w;
        }
        float o0 = (w0 > 0.f ? n0 / w0 : 0.f) + b20;
        float o1 = (w1 > 0.f ? n1 / w1 : 0.f) + b21;
        if (rel == 0) { o.x = o0; o.y = o1; } else { o.z = o0; o.w = o1; }
    }
    *(float4*)(out + (long)d * 4) = o;
}

extern "C" void kernel_launch(void* const* d_in, const int* in_sizes, int n_in,
                              void* d_out, int out_size, void* d_ws, size_t ws_size,
                              hipStream_t stream) {
    const float* x   = (const float*)d_in[0];
    const float* W1  = (const float*)d_in[1];
    const float* aL1 = (const float*)d_in[2];
    const float* aR1 = (const float*)d_in[3];
    const float* b1  = (const float*)d_in[4];
    const float* W2  = (const float*)d_in[5];
    const float* aL2 = (const float*)d_in[6];
    const float* aR2 = (const float*)d_in[7];
    const float* b2  = (const float*)d_in[8];
    const int* srcF  = (const int*)d_in[9];
    const int* dstF  = (const int*)d_in[10];
    const int* srcL  = (const int*)d_in[11];
    const int* dstL  = (const int*)d_in[12];
    float* out = (float*)d_out;

    const int N = in_sizes[0] / 32;
    const int E = in_sizes[9];
    const int tiles = (N + TILE1 - 1) / TILE1;  // 8 for N=50000

    // Workspace: g 8N | el1 2N | er1 2N | h2 2N | bk 16 | pw 384 | partial1 | partial2
    float* ws   = (float*)d_ws;
    float* g    = ws;                             // 8N
    float* el1  = g + (long)8 * N;                // 2N
    float* er1  = el1 + (long)2 * N;              // 2N
    float* h2   = er1 + (long)2 * N;              // 2N
    float* bk   = h2 + (long)2 * N;               // 16
    float* pw   = bk + 16;                        // 384
    float* partial1 = pw + 384;                   // 2*tiles*SLICES*TILE1*6 (= 38.4 MB)
    float* partial2 = partial1 + (long)2 * tiles * SLICES * TILE1 * 6;  // (= 25.6 MB)
    // total ~= 67 MB (ws >= 81 MB proven in round 2)

    k_precomp<<<1, 512, 0, stream>>>(W1, aL1, aR1, W2, b1, pw, bk);
    k_proj<<<(N + 255) / 256, 256, 0, stream>>>(x, pw, el1, er1, g, N);

    dim3 agrid(SLICES, tiles, 2);
    k_agg1t<<<agrid, 1024, 0, stream>>>(srcF, dstF, srcL, dstL, el1, er1, g, partial1, E, tiles);
    k_merge1<<<(N + 255) / 256, 256, 0, stream>>>(partial1, bk, h2, N, tiles);
    k_agg2t<<<agrid, 1024, 0, stream>>>(srcF, dstF, srcL, dstL, h2, aL2, aR2, partial2, E, tiles);
    k_merge2<<<(N + 255) / 256, 256, 0, stream>>>(partial2, b2, out, N, tiles);
}